// Round 3
// baseline (293.631 us; speedup 1.0000x reference)
//
#include <hip/hip_runtime.h>
#include <stdint.h>

#define B_N   8192
#define D_K   626
#define KPAD  640        // fp8 bytes per row (padded)
#define BK64  64         // K-bytes per pipeline step (R15)
#define NT    10         // KPAD / BK64
#define BMN   256        // square output tile per block (R15)
#define FIN_BLOCKS 16

typedef __attribute__((ext_vector_type(4))) int   i32x4;
typedef __attribute__((ext_vector_type(8))) int   i32x8;
typedef __attribute__((ext_vector_type(16))) float f32x16;

__device__ __forceinline__ void async16(const unsigned char* g, unsigned char* l) {
    __builtin_amdgcn_global_load_lds(
        (const __attribute__((address_space(1))) unsigned int*)(const void*)g,
        (__attribute__((address_space(3))) unsigned int*)(void*)l,
        16, 0, 0);
}

// ---------------- Kernel 1: row-normalize + convert to fp8 e4m3 (padded K) --
// R13: 2 rows/wave, 2048 blocks = 8 blocks/CU -> full occupancy, ~10 us.
// (dur_us tracks ~2.0x gemm only, 3 rounds running; off critical path.)
__global__ __launch_bounds__(256) void normalize_kernel(
    const float* __restrict__ A, const float* __restrict__ P,
    unsigned char* __restrict__ Af8, unsigned char* __restrict__ Pf8,
    float* __restrict__ rowexp, float* __restrict__ rowsum, float* __restrict__ acc)
{
    const int which = blockIdx.y;
    const float* srcM = which ? P : A;
    unsigned char* dstM = which ? Pf8 : Af8;
    const int t  = threadIdx.x;
    const int wv = t >> 6;
    const int L  = t & 63;
    const int rowBase = blockIdx.x * 8 + wv * 2;

    if (which == 0) {
        const int rb = blockIdx.x * 8;
        if (t < 8) { rowexp[rb + t] = 0.0f; rowsum[rb + t] = 0.0f; }
        if (blockIdx.x == 0 && t < 4) acc[t] = 0.0f;   // acc[3] = finalize done-counter
    }

    #pragma unroll
    for (int j = 0; j < 2; ++j) {
        const int r = rowBase + j;
        const float2* s2 = (const float2*)(srcM + (size_t)r * D_K);

        float2 a0 = s2[2 * L];       float2 a1 = s2[2 * L + 1];       // ints 0..63
        float2 b0 = s2[2 * L + 128]; float2 b1 = s2[2 * L + 129];     // ints 64..127
        float2 c0 = {0.f, 0.f},      c1 = {0.f, 0.f};                 // ints 128..159
        if (L < 28)       { c0 = s2[2 * L + 256]; c1 = s2[2 * L + 257]; }
        else if (L == 28) { c0 = s2[312]; }                            // floats 624,625

        float ss = a0.x * a0.x + a0.y * a0.y + a1.x * a1.x + a1.y * a1.y
                 + b0.x * b0.x + b0.y * b0.y + b1.x * b1.x + b1.y * b1.y
                 + c0.x * c0.x + c0.y * c0.y + c1.x * c1.x + c1.y * c1.y;
        #pragma unroll
        for (int off = 32; off; off >>= 1) ss += __shfl_xor(ss, off, 64);
        const float rn = rsqrtf(ss);   // norms ~25, eps never active

        int* d4 = (int*)(dstM + (size_t)r * KPAD);
        int pk0 = __builtin_amdgcn_cvt_pk_fp8_f32(a0.x * rn, a0.y * rn, 0, false);
        pk0 = __builtin_amdgcn_cvt_pk_fp8_f32(a1.x * rn, a1.y * rn, pk0, true);
        d4[L] = pk0;
        int pk1 = __builtin_amdgcn_cvt_pk_fp8_f32(b0.x * rn, b0.y * rn, 0, false);
        pk1 = __builtin_amdgcn_cvt_pk_fp8_f32(b1.x * rn, b1.y * rn, pk1, true);
        d4[L + 64] = pk1;
        if (L < 32) {
            int pk2 = __builtin_amdgcn_cvt_pk_fp8_f32(c0.x * rn, c0.y * rn, 0, false);
            pk2 = __builtin_amdgcn_cvt_pk_fp8_f32(c1.x * rn, c1.y * rn, pk2, true);
            d4[L + 128] = pk2;
        }
    }
}

// ---------------- Kernel 2: fused fp8 cosine-GEMM + row reductions ----------
// R15: counted-vmcnt triple-buffer restructure (T3+T4+T5 per the guide).
//   R14 post-mortem: conflicts 5.24M -> 0 but time 76 -> 75 us. Regime-gate
//   confirmed (m252): in a 2-phase drain loop the critical path is
//   stage+vmcnt(0)+barrier; with depth-1 dbuf, ALL outstanding loads are for
//   the next buffer -> drain is structural. Fix needs prefetch depth >= 2.
// Structure: 256x256 tile/block, 8 waves (4 row x 2 col), BK=64 B, 3 LDS
//   buffers (96 KB, 1 block/CU), stage(t+2) issued at step t, barrier =
//   s_waitcnt vmcnt(4) + raw s_barrier (NEVER vmcnt(0) in the loop; peeled
//   last step uses vmcnt(0)). Per wave/step: 12 ds_read_b128, 8 independent
//   MFMAs wrapped in setprio(1)/(0).
// Safety (single barrier/step): every ds_read is consumed by an MFMA before
//   the barrier (compiler lgkm waits) -> reads COMPLETE before barrier entry;
//   stage into buffer (t-1)%3 is issued only after barrier exit. vmcnt(4)
//   counts exactly the 4 async16/wave/step (no other VMEM in loop).
// Swizzle (rule #21, both-sides involution): 4 slots/row, key=(rA>>1)&3 on
//   stage source and read; worst-case 2-way bank aliasing = free (m136).
// Ledger (do NOT retry):
//  - R8: min-waves=4 -> forced 64 VGPR -> scratch spill (2x slower)
//  - R9: BK=64 under DRAIN-per-barrier -> 2x slower (mechanism removed here:
//    counted vmcnt never drains; do not confuse with this change)
//  - R10: fused exit-path __threadfence -> L2 writeback storm (2x slower)
//  - R12: A direct global->VGPR -> in-order vmcnt drains B prefetch (2x)
//  - R14: swizzle alone at 2-phase: conflicts->0 but no time gain (gated)
__global__ __launch_bounds__(512, 2) void gemm_fused_kernel(
    const unsigned char* __restrict__ Af8, const unsigned char* __restrict__ Pf8,
    float* __restrict__ rowexp, float* __restrict__ rowsum, float* __restrict__ diag)
{
    __shared__ __align__(16) unsigned char sA[3][BMN * BK64];   // 48 KB
    __shared__ __align__(16) unsigned char sB[3][BMN * BK64];   // 48 KB

    const int t    = threadIdx.x;
    const int lane = t & 63;
    const int w    = t >> 6;      // 0..7
    const int wr   = w >> 1;      // wave row (0..3): rows wr*64 .. +63
    const int wc   = w & 1;       // wave col (0..1): cols wc*128 .. +127
    const int rA   = lane & 31;
    const int h    = lane >> 5;   // K-half selector (which 32 of the 64 k-bytes)
    const int key  = (rA >> 1) & 3;   // R15 swizzle key (4 slots/row)

    // XCD-chunked block swizzle (1024 blocks, 1024%8==0 -> bijective)
    const int bid  = blockIdx.x;
    const int swz  = (bid & 7) * 128 + (bid >> 3);
    const int rowBase = (swz >> 5) * BMN;
    const int colBase = (swz & 31) * BMN;

    const unsigned char* Ab = Af8 + (size_t)rowBase * KPAD;
    const unsigned char* Pb = Pf8 + (size_t)colBase * KPAD;

    // staging: 1024 16B-chunks per matrix per step; 2 chunks/matrix/thread.
    // LDS chunk q = (row<<2)|slot, linear dest; source slot = slot ^ key(row).
    const int q0 = t, q1 = t + 512;
    const int r0 = q0 >> 2, r1 = q1 >> 2;
    const size_t gsrc0 = (size_t)r0 * KPAD + (size_t)(((q0 & 3) ^ ((r0 >> 1) & 3)) * 16);
    const size_t gsrc1 = (size_t)r1 * KPAD + (size_t)(((q1 & 3) ^ ((r1 >> 1) & 3)) * 16);

    auto stage = [&](int buf, int kt) {
        const size_t kOff = (size_t)kt * BK64;
        async16(Ab + kOff + gsrc0, &sA[buf][q0 * 16]);
        async16(Ab + kOff + gsrc1, &sA[buf][q1 * 16]);
        async16(Pb + kOff + gsrc0, &sB[buf][q0 * 16]);
        async16(Pb + kOff + gsrc1, &sB[buf][q1 * 16]);
    };

    // fragment read offsets: logical chunks (2h, 2h+1) -> physical via key
    const int s0 = ((2 * h)     ^ key) * 16;
    const int s1 = ((2 * h + 1) ^ key) * 16;   // == s0 ^ 16

    f32x16 acc[2][4];   // [mi: 2 x 32-row blocks][ni: 4 x 32-col blocks]
    const f32x16 z16 = {0.f,0.f,0.f,0.f,0.f,0.f,0.f,0.f,
                        0.f,0.f,0.f,0.f,0.f,0.f,0.f,0.f};
    #pragma unroll
    for (int mi = 0; mi < 2; ++mi)
        #pragma unroll
        for (int ni = 0; ni < 4; ++ni) acc[mi][ni] = z16;

    auto compute = [&](int buf) {
        i32x8 aF[2], bF[4];
        #pragma unroll
        for (int mi = 0; mi < 2; ++mi) {
            const unsigned char* base = &sA[buf][(wr * 64 + mi * 32 + rA) * BK64];
            i32x4 lo = *(const i32x4*)(base + s0);
            i32x4 hi = *(const i32x4*)(base + s1);
            aF[mi] = __builtin_shufflevector(lo, hi, 0, 1, 2, 3, 4, 5, 6, 7);
        }
        #pragma unroll
        for (int ni = 0; ni < 4; ++ni) {
            const unsigned char* base = &sB[buf][(wc * 128 + ni * 32 + rA) * BK64];
            i32x4 lo = *(const i32x4*)(base + s0);
            i32x4 hi = *(const i32x4*)(base + s1);
            bF[ni] = __builtin_shufflevector(lo, hi, 0, 1, 2, 3, 4, 5, 6, 7);
        }
        __builtin_amdgcn_s_setprio(1);
        #pragma unroll
        for (int mi = 0; mi < 2; ++mi)
            #pragma unroll
            for (int ni = 0; ni < 4; ++ni)
                acc[mi][ni] = __builtin_amdgcn_mfma_scale_f32_32x32x64_f8f6f4(
                    aF[mi], bF[ni], acc[mi][ni],
                    0 /*A: fp8 e4m3*/, 0 /*B: fp8 e4m3*/,
                    0, 0x7F /*scaleA=2^0*/, 0, 0x7F /*scaleB=2^0*/);
        __builtin_amdgcn_s_setprio(0);
    };

    // prologue: depth-2 prefetch
    stage(0, 0);
    stage(1, 1);

    int cur = 0;
    #pragma unroll 1
    for (int kt = 0; kt < NT - 1; ++kt) {
        asm volatile("s_waitcnt vmcnt(4)" ::: "memory");   // stage(kt) landed
        __builtin_amdgcn_s_barrier();
        if (kt < NT - 2) {
            int sb = cur + 2; if (sb >= 3) sb -= 3;        // (kt+2) % 3
            stage(sb, kt + 2);
        }
        compute(cur);
        ++cur; if (cur == 3) cur = 0;
    }
    // peeled last step: only here do we drain to 0
    asm volatile("s_waitcnt vmcnt(0)" ::: "memory");
    __builtin_amdgcn_s_barrier();
    compute(cur);

    // ----- epilogue: registers only ------------------------------------
    // C/D layout: col = rA, row = (rg&3) + 8*(rg>>2) + 4*h   (verified R13/14)
    if (rowBase == colBase) {   // diagonal block: 32 of 1024
        #pragma unroll
        for (int mi = 0; mi < 2; ++mi)
            #pragma unroll
            for (int ni = 0; ni < 4; ++ni)
                if (wr * 64 + mi * 32 == wc * 128 + ni * 32) {  // wave-uniform
                    #pragma unroll
                    for (int rg = 0; rg < 16; ++rg) {
                        const int row32 = (rg & 3) + 8 * (rg >> 2) + 4 * h;
                        if (rA == row32)
                            diag[rowBase + wr * 64 + mi * 32 + row32] = acc[mi][ni][rg];
                    }
                }
    }

    #pragma unroll
    for (int mi = 0; mi < 2; ++mi) {
        #pragma unroll
        for (int rg = 0; rg < 16; ++rg) {
            float s = 0.f, e = 0.f;
            #pragma unroll
            for (int ni = 0; ni < 4; ++ni) {
                const float S = acc[mi][ni][rg];
                s += S;
                e += __expf(S * 4.0f);         // logits = S / 0.25
            }
            #pragma unroll
            for (int off = 1; off <= 16; off <<= 1) {   // reduce 32 cols, keep h
                s += __shfl_xor(s, off, 64);
                e += __shfl_xor(e, off, 64);
            }
            if (rA == 0) {   // lanes 0 / 32 hold h=0 / h=1 row groups
                const int gr = rowBase + wr * 64 + mi * 32
                             + (rg & 3) + 8 * (rg >> 2) + 4 * h;
                atomicAdd(&rowsum[gr], s);
                atomicAdd(&rowexp[gr], e);
            }
        }
    }
}

// ---------------- Kernel 3: final reduction + device-side completion --------
__global__ __launch_bounds__(256) void finalize_kernel(
    const float* __restrict__ rowexp, const float* __restrict__ rowsum,
    const float* __restrict__ diag, float* __restrict__ acc, float* __restrict__ out)
{
    const int t = threadIdx.x;
    float ls = 0.f, ds = 0.f, ns = 0.f;
    for (int i = blockIdx.x * 256 + t; i < B_N; i += FIN_BLOCKS * 256) {
        const float d = diag[i];
        ls += __logf(rowexp[i]) - d * 4.0f;   // logsumexp - diag_logit
        ds += d;
        ns += (rowsum[i] - d);
    }
    #pragma unroll
    for (int off = 32; off; off >>= 1) {
        ls += __shfl_down(ls, off, 64);
        ds += __shfl_down(ds, off, 64);
        ns += __shfl_down(ns, off, 64);
    }
    __shared__ float sl[4], sd[4], sn[4];
    if ((t & 63) == 0) { sl[t >> 6] = ls; sd[t >> 6] = ds; sn[t >> 6] = ns; }
    __syncthreads();
    if (t == 0) {
        atomicAdd(acc + 0, sl[0] + sl[1] + sl[2] + sl[3]);
        atomicAdd(acc + 1, sd[0] + sd[1] + sd[2] + sd[3]);
        atomicAdd(acc + 2, sn[0] + sn[1] + sn[2] + sn[3]);
        __threadfence();
        const int done = (int)atomicAdd((unsigned int*)(acc + 3), 1u);
        if (done == FIN_BLOCKS - 1) {
            const float L  = atomicAdd(acc + 0, 0.0f);   // coherent reads
            const float Dm = atomicAdd(acc + 1, 0.0f);
            const float Nn = atomicAdd(acc + 2, 0.0f);
            out[0] = L / (float)B_N;
            out[1] = Dm / (float)B_N;
            out[2] = (Nn / (float)(B_N - 1)) / (float)B_N;
        }
    }
}

// ---------------- Fallback path (small workspace): fp32 vector --------------
__global__ __launch_bounds__(256) void fb_norm(
    const float* __restrict__ A, const float* __restrict__ P,
    float* __restrict__ rna, float* __restrict__ rnp, float* __restrict__ acc)
{
    const int r = blockIdx.x;
    const float* src = blockIdx.y ? P : A;
    const int t = threadIdx.x;
    float ss = 0.f;
    for (int k = t; k < D_K; k += 256) { float v = src[(size_t)r * D_K + k]; ss += v * v; }
    #pragma unroll
    for (int off = 32; off; off >>= 1) ss += __shfl_down(ss, off, 64);
    __shared__ float sred[4];
    if ((t & 63) == 0) sred[t >> 6] = ss;
    __syncthreads();
    if (t == 0) {
        const float rn = rsqrtf(sred[0] + sred[1] + sred[2] + sred[3]);
        (blockIdx.y ? rnp : rna)[r] = rn;
    }
    if (blockIdx.x == 0 && blockIdx.y == 0 && t < 3) acc[t] = 0.0f;
}

__global__ __launch_bounds__(256) void fb_main(
    const float* __restrict__ A, const float* __restrict__ P,
    const float* __restrict__ rna, const float* __restrict__ rnp,
    float* __restrict__ acc)
{
    __shared__ float sa[D_K];
    __shared__ float red[12];
    const int i = blockIdx.x;
    const int t = threadIdx.x;
    const float rn = rna[i];
    for (int k = t; k < D_K; k += 256) sa[k] = A[(size_t)i * D_K + k] * rn;
    __syncthreads();
    const int w = t >> 6, lane = t & 63;
    float we = 0.f, wsum = 0.f, wd = 0.f;
    for (int j = w; j < B_N; j += 4) {
        float dot = 0.f;
        const float* p = P + (size_t)j * D_K;
        for (int k = lane; k < D_K; k += 64) dot += sa[k] * p[k];
        #pragma unroll
        for (int off = 32; off; off >>= 1) dot += __shfl_xor(dot, off, 64);
        const float S = dot * rnp[j];
        we += __expf(S * 4.0f);
        wsum += S;
        if (j == i) wd = S;
    }
    if (lane == 0) { red[w] = we; red[4 + w] = wsum; red[8 + w] = wd; }
    __syncthreads();
    if (t == 0) {
        const float E  = red[0] + red[1] + red[2] + red[3];
        const float Sm = red[4] + red[5] + red[6] + red[7];
        const float Dd = red[8] + red[9] + red[10] + red[11];
        atomicAdd(acc + 0, __logf(E) - 4.0f * Dd);
        atomicAdd(acc + 1, Dd);
        atomicAdd(acc + 2, Sm - Dd);
    }
}

__global__ void fb_fin(const float* __restrict__ acc, float* __restrict__ out)
{
    out[0] = acc[0] / (float)B_N;
    out[1] = acc[1] / (float)B_N;
    out[2] = acc[2] / ((float)(B_N - 1) * (float)B_N);
}

// ---------------------------------------------------------------------------
extern "C" void kernel_launch(void* const* d_in, const int* in_sizes, int n_in,
                              void* d_out, int out_size, void* d_ws, size_t ws_size,
                              hipStream_t stream)
{
    const float* A = (const float*)d_in[0];
    const float* P = (const float*)d_in[1];
    float* out = (float*)d_out;
    char* ws = (char*)d_ws;

    const size_t AF8_OFF  = 0;
    const size_t PF8_OFF  = AF8_OFF + (size_t)B_N * KPAD;
    const size_t REXP_OFF = PF8_OFF + (size_t)B_N * KPAD;
    const size_t RSUM_OFF = REXP_OFF + (size_t)B_N * sizeof(float);
    const size_t DIAG_OFF = RSUM_OFF + (size_t)B_N * sizeof(float);
    const size_t ACC_OFF  = DIAG_OFF + (size_t)B_N * sizeof(float);
    const size_t MAIN_REQ = ACC_OFF + 16;

    if (ws_size >= MAIN_REQ) {
        unsigned char* Af8 = (unsigned char*)(ws + AF8_OFF);
        unsigned char* Pf8 = (unsigned char*)(ws + PF8_OFF);
        float* rowexp = (float*)(ws + REXP_OFF);
        float* rowsum = (float*)(ws + RSUM_OFF);
        float* diag   = (float*)(ws + DIAG_OFF);
        float* acc    = (float*)(ws + ACC_OFF);

        normalize_kernel<<<dim3(B_N / 8, 2), 256, 0, stream>>>(A, P, Af8, Pf8,
                                                               rowexp, rowsum, acc);
        gemm_fused_kernel<<<dim3((B_N / BMN) * (B_N / BMN)), 512, 0, stream>>>(
            Af8, Pf8, rowexp, rowsum, diag);
        finalize_kernel<<<FIN_BLOCKS, 256, 0, stream>>>(rowexp, rowsum, diag, acc, out);
    } else {
        // slow-but-correct fp32 fallback (needs ~96 KB ws)
        float* rna = (float*)ws;
        float* rnp = rna + B_N;
        float* acc = rnp + B_N;
        fb_norm<<<dim3(B_N, 2), 256, 0, stream>>>(A, P, rna, rnp, acc);
        fb_main<<<B_N, 256, 0, stream>>>(A, P, rna, rnp, acc);
        fb_fin<<<1, 1, 0, stream>>>(acc, out);
    }
}

// Round 4
// 161.969 us; speedup vs baseline: 1.8129x; 1.8129x over previous
//
#include <hip/hip_runtime.h>
#include <stdint.h>

#define B_N   8192
#define D_K   626
#define KPAD  640        // fp8 bytes per row (padded)
#define BK    64         // K-bytes per pipeline step (R16)
#define KSTEPS_CT 10     // K-steps per col-tile (KPAD/BK)
#define BM    128
#define BN    128
#define COL_CHUNKS 16
#define TILES_PER_CHUNK 4   // 8192 / (16*128)
#define NSTEPS 40           // TILES_PER_CHUNK * KSTEPS_CT
#define FIN_BLOCKS 16

typedef __attribute__((ext_vector_type(4))) int   i32x4;
typedef __attribute__((ext_vector_type(8))) int   i32x8;
typedef __attribute__((ext_vector_type(16))) float f32x16;

__device__ __forceinline__ void async16(const unsigned char* g, unsigned char* l) {
    __builtin_amdgcn_global_load_lds(
        (const __attribute__((address_space(1))) unsigned int*)(const void*)g,
        (__attribute__((address_space(3))) unsigned int*)(void*)l,
        16, 0, 0);
}

// ---------------- Kernel 1: row-normalize + convert to fp8 e4m3 (padded K) --
// R13: 2 rows/wave, 2048 blocks = 8 blocks/CU -> full occupancy, ~10 us.
// (dur_us tracks ~2.0x gemm only, 4 rounds running; off critical path.)
__global__ __launch_bounds__(256) void normalize_kernel(
    const float* __restrict__ A, const float* __restrict__ P,
    unsigned char* __restrict__ Af8, unsigned char* __restrict__ Pf8,
    float* __restrict__ rowexp, float* __restrict__ rowsum, float* __restrict__ acc)
{
    const int which = blockIdx.y;
    const float* srcM = which ? P : A;
    unsigned char* dstM = which ? Pf8 : Af8;
    const int t  = threadIdx.x;
    const int wv = t >> 6;
    const int L  = t & 63;
    const int rowBase = blockIdx.x * 8 + wv * 2;

    if (which == 0) {
        const int rb = blockIdx.x * 8;
        if (t < 8) { rowexp[rb + t] = 0.0f; rowsum[rb + t] = 0.0f; }
        if (blockIdx.x == 0 && t < 4) acc[t] = 0.0f;   // acc[3] = finalize done-counter
    }

    #pragma unroll
    for (int j = 0; j < 2; ++j) {
        const int r = rowBase + j;
        const float2* s2 = (const float2*)(srcM + (size_t)r * D_K);

        float2 a0 = s2[2 * L];       float2 a1 = s2[2 * L + 1];       // ints 0..63
        float2 b0 = s2[2 * L + 128]; float2 b1 = s2[2 * L + 129];     // ints 64..127
        float2 c0 = {0.f, 0.f},      c1 = {0.f, 0.f};                 // ints 128..159
        if (L < 28)       { c0 = s2[2 * L + 256]; c1 = s2[2 * L + 257]; }
        else if (L == 28) { c0 = s2[312]; }                            // floats 624,625

        float ss = a0.x * a0.x + a0.y * a0.y + a1.x * a1.x + a1.y * a1.y
                 + b0.x * b0.x + b0.y * b0.y + b1.x * b1.x + b1.y * b1.y
                 + c0.x * c0.x + c0.y * c0.y + c1.x * c1.x + c1.y * c1.y;
        #pragma unroll
        for (int off = 32; off; off >>= 1) ss += __shfl_xor(ss, off, 64);
        const float rn = rsqrtf(ss);   // norms ~25, eps never active

        int* d4 = (int*)(dstM + (size_t)r * KPAD);
        int pk0 = __builtin_amdgcn_cvt_pk_fp8_f32(a0.x * rn, a0.y * rn, 0, false);
        pk0 = __builtin_amdgcn_cvt_pk_fp8_f32(a1.x * rn, a1.y * rn, pk0, true);
        d4[L] = pk0;
        int pk1 = __builtin_amdgcn_cvt_pk_fp8_f32(b0.x * rn, b0.y * rn, 0, false);
        pk1 = __builtin_amdgcn_cvt_pk_fp8_f32(b1.x * rn, b1.y * rn, pk1, true);
        d4[L + 64] = pk1;
        if (L < 32) {
            int pk2 = __builtin_amdgcn_cvt_pk_fp8_f32(c0.x * rn, c0.y * rn, 0, false);
            pk2 = __builtin_amdgcn_cvt_pk_fp8_f32(c1.x * rn, c1.y * rn, pk2, true);
            d4[L + 128] = pk2;
        }
    }
}

// ---------------- Kernel 2: fused fp8 cosine-GEMM + row reductions ----------
// R16: counted-vmcnt pipeline INSIDE the R14-proven envelope.
// R15 post-mortem (217 us): the 256^2/1-block-per-CU restructure destroyed
//   locality (FETCH 23->84 MB: XCD swizzle put the same B panel on all 8
//   XCDs, per-XCD set 5.9MB > 4MB L2 -> B streamed at 473 GB/s latency-bound)
//   and halved TLP. The counted-vmcnt mechanism itself verified correct.
// R16 structure: (64,16) grid natural order (R14: 95% L2 hit), 128x128 tile,
//   4 waves (2x2), 2 blocks/CU. BK=64, FOUR LDS buffers (64 KB), depth-3
//   prefetch: stage(s+3) after barrier s; wait vmcnt(8) retires stage(s)
//   only (8 = stages s+1,s+2 in flight); tail peels 4/0. WAR safe: buf s&3
//   is rewritten by stage(s+4) issued after barrier s+1, and all reads of
//   it completed before entering barrier s+1 (lgkm waits precede MFMA use).
// LDS zero-conflict geometry (R14-proven isomorphism): pack two 64-B rows
//   per 128-B superrow (stride = 32 banks), 8x16B slots, key(sr) =
//   (sr&7)^((sr>>3)&1), applied to stage SOURCE and read (involution,
//   rule #21). 8 consecutive lanes hit 8 distinct slots.
// Ledger (do NOT retry):
//  - R8: min-waves=4 -> forced 64 VGPR -> scratch spill (2x slower)
//  - R9: BK=64 under DRAIN-per-barrier -> 2x (drain removed here)
//  - R10: fused exit-path __threadfence -> L2 writeback storm (2x)
//  - R12: A direct global->VGPR -> in-order vmcnt drains B prefetch (2x)
//  - R14: swizzle alone under 2-phase drain: conflicts->0, time ~0 (gated)
//  - R15: 256^2 tile + 1 block/CU + same-panel-across-XCD swizzle: FETCH 3.6x,
//    latency-bound stream, 2.9x slower. Keep (64,16) natural grid.
__global__ __launch_bounds__(256, 2) void gemm_fused_kernel(
    const unsigned char* __restrict__ Af8, const unsigned char* __restrict__ Pf8,
    float* __restrict__ rowexp, float* __restrict__ rowsum, float* __restrict__ diag)
{
    __shared__ __align__(16) unsigned char sA[4][BM * BK];   // 32 KB
    __shared__ __align__(16) unsigned char sB[4][BN * BK];   // 32 KB

    const int t    = threadIdx.x;
    const int lane = t & 63;
    const int w    = t >> 6;
    const int wr   = w >> 1;      // wave row (0..1): rows wr*64..+63
    const int wc   = w & 1;       // wave col (0..1): cols wc*64..+63
    const int rA   = lane & 31;   // row within a 32-row block
    const int h    = lane >> 5;   // K-half selector (which 32 of the 64 k-bytes)
    const int par4 = (rA & 1) * 4;          // row parity -> logical slot half
    const int srA0 = wr * 32 + (rA >> 1);   // superrow for mi=0 (A side)
    const int srB0 = wc * 32 + (rA >> 1);   // superrow for ni=0 (B side)

    const int rowBase = blockIdx.x * BM;       // 64 row-tiles
    const int chunk   = blockIdx.y;            // 16 col-chunks

    const unsigned char* Ab = Af8 + (size_t)rowBase * KPAD;
    const unsigned char* PbChunk = Pf8 + (size_t)(chunk * TILES_PER_CHUNK) * BN * KPAD;

    // staging: per matrix per step 512 chunks of 16 B (64 superrows x 8 slots);
    // 2 chunks/thread. LDS dest linear (q*16); source slot = p ^ key(sr).
    const int q0 = t, q1 = t + 256;
    const int sr0 = q0 >> 3, p0s = q0 & 7;
    const int sr1 = q1 >> 3, p1s = q1 & 7;
    const int l0 = p0s ^ ((sr0 & 7) ^ ((sr0 >> 3) & 1));
    const int l1 = p1s ^ ((sr1 & 7) ^ ((sr1 >> 3) & 1));
    const int gA0 = (2 * sr0 + (l0 >> 2)) * KPAD + (l0 & 3) * 16;
    const int gA1 = (2 * sr1 + (l1 >> 2)) * KPAD + (l1 & 3) * 16;

    auto stage = [&](int buf, int ct, int ks) {
        const unsigned char* AbT = Ab + ks * BK;
        const unsigned char* PbT = PbChunk + (size_t)ct * BN * KPAD + ks * BK;
        async16(AbT + gA0, &sA[buf][q0 * 16]);
        async16(AbT + gA1, &sA[buf][q1 * 16]);
        async16(PbT + gA0, &sB[buf][q0 * 16]);
        async16(PbT + gA1, &sB[buf][q1 * 16]);
    };

    // persistent per-lane row partials: [mi][reg]
    float psum[2][16], pexp[2][16];
    #pragma unroll
    for (int i = 0; i < 2; ++i)
        #pragma unroll
        for (int j = 0; j < 16; ++j) { psum[i][j] = 0.0f; pexp[i][j] = 0.0f; }

    const f32x16 z16 = {0.f,0.f,0.f,0.f,0.f,0.f,0.f,0.f,
                        0.f,0.f,0.f,0.f,0.f,0.f,0.f,0.f};
    f32x16 acc[2][2];   // [mi][ni], each 32x32
    acc[0][0] = z16; acc[0][1] = z16; acc[1][0] = z16; acc[1][1] = z16;

    auto compute = [&](int buf) {
        i32x8 aF[2], bF[2];
        #pragma unroll
        for (int mi = 0; mi < 2; ++mi) {
            const int sr  = srA0 + mi * 16;
            const int key = (sr & 7) ^ ((sr >> 3) & 1);
            const int s0  = ((par4 + 2 * h) ^ key) * 16;
            const unsigned char* base = &sA[buf][sr * 128];
            i32x4 lo = *(const i32x4*)(base + s0);
            i32x4 hi = *(const i32x4*)(base + (s0 ^ 16));
            aF[mi] = __builtin_shufflevector(lo, hi, 0, 1, 2, 3, 4, 5, 6, 7);
        }
        #pragma unroll
        for (int ni = 0; ni < 2; ++ni) {
            const int sr  = srB0 + ni * 16;
            const int key = (sr & 7) ^ ((sr >> 3) & 1);
            const int s0  = ((par4 + 2 * h) ^ key) * 16;
            const unsigned char* base = &sB[buf][sr * 128];
            i32x4 lo = *(const i32x4*)(base + s0);
            i32x4 hi = *(const i32x4*)(base + (s0 ^ 16));
            bF[ni] = __builtin_shufflevector(lo, hi, 0, 1, 2, 3, 4, 5, 6, 7);
        }
        __builtin_amdgcn_s_setprio(1);
        #pragma unroll
        for (int mi = 0; mi < 2; ++mi)
            #pragma unroll
            for (int ni = 0; ni < 2; ++ni)
                acc[mi][ni] = __builtin_amdgcn_mfma_scale_f32_32x32x64_f8f6f4(
                    aF[mi], bF[ni], acc[mi][ni],
                    0 /*A: fp8 e4m3*/, 0 /*B: fp8 e4m3*/,
                    0, 0x7F /*scaleA=2^0*/, 0, 0x7F /*scaleB=2^0*/);
        __builtin_amdgcn_s_setprio(0);
    };

    auto epilogue = [&](int cct) {
        const int colBase = (chunk * TILES_PER_CHUNK + cct) * BN;
        // C/D layout: col = rA, row = (rg&3) + 8*(rg>>2) + 4*h  (verified R13/14)
        if (rowBase == colBase && wr == wc) {   // diagonal sub-blocks: ni == mi
            #pragma unroll
            for (int mi = 0; mi < 2; ++mi)
                #pragma unroll
                for (int rg = 0; rg < 16; ++rg) {
                    const int row32 = (rg & 3) + 8 * (rg >> 2) + 4 * h;
                    if (rA == row32)
                        diag[rowBase + wr * 64 + mi * 32 + row32] = acc[mi][mi][rg];
                }
        }
        #pragma unroll
        for (int mi = 0; mi < 2; ++mi) {
            #pragma unroll
            for (int rg = 0; rg < 16; ++rg) {
                const float S0 = acc[mi][0][rg];
                const float S1 = acc[mi][1][rg];
                psum[mi][rg] += S0 + S1;
                pexp[mi][rg] += __expf(S0 * 4.0f) + __expf(S1 * 4.0f);  // logits=S/0.25
            }
        }
        acc[0][0] = z16; acc[0][1] = z16; acc[1][0] = z16; acc[1][1] = z16;
    };

    // prologue: depth-3 prefetch
    stage(0, 0, 0);
    stage(1, 0, 1);
    stage(2, 0, 2);

    int sct = 0, sks = 3;   // coords of stage target s+3
    int cct = 0, cks = 0;   // coords of compute step s
    #pragma unroll 1
    for (int s = 0; s < NSTEPS; ++s) {
        if (s < NSTEPS - 2)       asm volatile("s_waitcnt vmcnt(8)" ::: "memory");
        else if (s == NSTEPS - 2) asm volatile("s_waitcnt vmcnt(4)" ::: "memory");
        else                      asm volatile("s_waitcnt vmcnt(0)" ::: "memory");
        __builtin_amdgcn_s_barrier();

        if (s + 3 < NSTEPS) {
            stage((s + 3) & 3, sct, sks);
            if (++sks == KSTEPS_CT) { sks = 0; ++sct; }
        }
        compute(s & 3);
        if (++cks == KSTEPS_CT) { cks = 0; epilogue(cct); ++cct; }
    }

    // reduce across the 32 columns (rA lanes; offsets <=16 preserve the h bit)
    #pragma unroll
    for (int off = 1; off <= 16; off <<= 1) {
        #pragma unroll
        for (int mi = 0; mi < 2; ++mi)
            #pragma unroll
            for (int rg = 0; rg < 16; ++rg) {
                psum[mi][rg] += __shfl_xor(psum[mi][rg], off, 64);
                pexp[mi][rg] += __shfl_xor(pexp[mi][rg], off, 64);
            }
    }
    if (rA == 0) {   // lanes 0 / 32 hold h=0 / h=1 row groups
        #pragma unroll
        for (int mi = 0; mi < 2; ++mi)
            #pragma unroll
            for (int rg = 0; rg < 16; ++rg) {
                const int gr = rowBase + wr * 64 + mi * 32
                             + (rg & 3) + 8 * (rg >> 2) + 4 * h;
                atomicAdd(&rowsum[gr], psum[mi][rg]);
                atomicAdd(&rowexp[gr], pexp[mi][rg]);
            }
    }
}

// ---------------- Kernel 3: final reduction + device-side completion --------
__global__ __launch_bounds__(256) void finalize_kernel(
    const float* __restrict__ rowexp, const float* __restrict__ rowsum,
    const float* __restrict__ diag, float* __restrict__ acc, float* __restrict__ out)
{
    const int t = threadIdx.x;
    float ls = 0.f, ds = 0.f, ns = 0.f;
    for (int i = blockIdx.x * 256 + t; i < B_N; i += FIN_BLOCKS * 256) {
        const float d = diag[i];
        ls += __logf(rowexp[i]) - d * 4.0f;   // logsumexp - diag_logit
        ds += d;
        ns += (rowsum[i] - d);
    }
    #pragma unroll
    for (int off = 32; off; off >>= 1) {
        ls += __shfl_down(ls, off, 64);
        ds += __shfl_down(ds, off, 64);
        ns += __shfl_down(ns, off, 64);
    }
    __shared__ float sl[4], sd[4], sn[4];
    if ((t & 63) == 0) { sl[t >> 6] = ls; sd[t >> 6] = ds; sn[t >> 6] = ns; }
    __syncthreads();
    if (t == 0) {
        atomicAdd(acc + 0, sl[0] + sl[1] + sl[2] + sl[3]);
        atomicAdd(acc + 1, sd[0] + sd[1] + sd[2] + sd[3]);
        atomicAdd(acc + 2, sn[0] + sn[1] + sn[2] + sn[3]);
        __threadfence();
        const int done = (int)atomicAdd((unsigned int*)(acc + 3), 1u);
        if (done == FIN_BLOCKS - 1) {
            const float L  = atomicAdd(acc + 0, 0.0f);   // coherent reads
            const float Dm = atomicAdd(acc + 1, 0.0f);
            const float Nn = atomicAdd(acc + 2, 0.0f);
            out[0] = L / (float)B_N;
            out[1] = Dm / (float)B_N;
            out[2] = (Nn / (float)(B_N - 1)) / (float)B_N;
        }
    }
}

// ---------------- Fallback path (small workspace): fp32 vector --------------
__global__ __launch_bounds__(256) void fb_norm(
    const float* __restrict__ A, const float* __restrict__ P,
    float* __restrict__ rna, float* __restrict__ rnp, float* __restrict__ acc)
{
    const int r = blockIdx.x;
    const float* src = blockIdx.y ? P : A;
    const int t = threadIdx.x;
    float ss = 0.f;
    for (int k = t; k < D_K; k += 256) { float v = src[(size_t)r * D_K + k]; ss += v * v; }
    #pragma unroll
    for (int off = 32; off; off >>= 1) ss += __shfl_down(ss, off, 64);
    __shared__ float sred[4];
    if ((t & 63) == 0) sred[t >> 6] = ss;
    __syncthreads();
    if (t == 0) {
        const float rn = rsqrtf(sred[0] + sred[1] + sred[2] + sred[3]);
        (blockIdx.y ? rnp : rna)[r] = rn;
    }
    if (blockIdx.x == 0 && blockIdx.y == 0 && t < 3) acc[t] = 0.0f;
}

__global__ __launch_bounds__(256) void fb_main(
    const float* __restrict__ A, const float* __restrict__ P,
    const float* __restrict__ rna, const float* __restrict__ rnp,
    float* __restrict__ acc)
{
    __shared__ float sa[D_K];
    __shared__ float red[12];
    const int i = blockIdx.x;
    const int t = threadIdx.x;
    const float rn = rna[i];
    for (int k = t; k < D_K; k += 256) sa[k] = A[(size_t)i * D_K + k] * rn;
    __syncthreads();
    const int w = t >> 6, lane = t & 63;
    float we = 0.f, wsum = 0.f, wd = 0.f;
    for (int j = w; j < B_N; j += 4) {
        float dot = 0.f;
        const float* p = P + (size_t)j * D_K;
        for (int k = lane; k < D_K; k += 64) dot += sa[k] * p[k];
        #pragma unroll
        for (int off = 32; off; off >>= 1) dot += __shfl_xor(dot, off, 64);
        const float S = dot * rnp[j];
        we += __expf(S * 4.0f);
        wsum += S;
        if (j == i) wd = S;
    }
    if (lane == 0) { red[w] = we; red[4 + w] = wsum; red[8 + w] = wd; }
    __syncthreads();
    if (t == 0) {
        const float E  = red[0] + red[1] + red[2] + red[3];
        const float Sm = red[4] + red[5] + red[6] + red[7];
        const float Dd = red[8] + red[9] + red[10] + red[11];
        atomicAdd(acc + 0, __logf(E) - 4.0f * Dd);
        atomicAdd(acc + 1, Dd);
        atomicAdd(acc + 2, Sm - Dd);
    }
}

__global__ void fb_fin(const float* __restrict__ acc, float* __restrict__ out)
{
    out[0] = acc[0] / (float)B_N;
    out[1] = acc[1] / (float)B_N;
    out[2] = acc[2] / ((float)(B_N - 1) * (float)B_N);
}

// ---------------------------------------------------------------------------
extern "C" void kernel_launch(void* const* d_in, const int* in_sizes, int n_in,
                              void* d_out, int out_size, void* d_ws, size_t ws_size,
                              hipStream_t stream)
{
    const float* A = (const float*)d_in[0];
    const float* P = (const float*)d_in[1];
    float* out = (float*)d_out;
    char* ws = (char*)d_ws;

    const size_t AF8_OFF  = 0;
    const size_t PF8_OFF  = AF8_OFF + (size_t)B_N * KPAD;
    const size_t REXP_OFF = PF8_OFF + (size_t)B_N * KPAD;
    const size_t RSUM_OFF = REXP_OFF + (size_t)B_N * sizeof(float);
    const size_t DIAG_OFF = RSUM_OFF + (size_t)B_N * sizeof(float);
    const size_t ACC_OFF  = DIAG_OFF + (size_t)B_N * sizeof(float);
    const size_t MAIN_REQ = ACC_OFF + 16;

    if (ws_size >= MAIN_REQ) {
        unsigned char* Af8 = (unsigned char*)(ws + AF8_OFF);
        unsigned char* Pf8 = (unsigned char*)(ws + PF8_OFF);
        float* rowexp = (float*)(ws + REXP_OFF);
        float* rowsum = (float*)(ws + RSUM_OFF);
        float* diag   = (float*)(ws + DIAG_OFF);
        float* acc    = (float*)(ws + ACC_OFF);

        normalize_kernel<<<dim3(B_N / 8, 2), 256, 0, stream>>>(A, P, Af8, Pf8,
                                                               rowexp, rowsum, acc);
        gemm_fused_kernel<<<dim3(B_N / BM, COL_CHUNKS), 256, 0, stream>>>(
            Af8, Pf8, rowexp, rowsum, diag);
        finalize_kernel<<<FIN_BLOCKS, 256, 0, stream>>>(rowexp, rowsum, diag, acc, out);
    } else {
        // slow-but-correct fp32 fallback (needs ~96 KB ws)
        float* rna = (float*)ws;
        float* rnp = rna + B_N;
        float* acc = rnp + B_N;
        fb_norm<<<dim3(B_N, 2), 256, 0, stream>>>(A, P, rna, rnp, acc);
        fb_main<<<B_N, 256, 0, stream>>>(A, P, rna, rnp, acc);
        fb_fin<<<1, 1, 0, stream>>>(acc, out);
    }
}